// Round 1
// baseline (401.286 us; speedup 1.0000x reference)
//
#include <hip/hip_runtime.h>
#include <math.h>

// Sizes (fixed by problem)
#define NB   128      // batch
#define CF   1024     // channels / K
#define RR   256      // spatial r = 16*16
#define NA   312      // n_att
#define DV   300      // dv
#define M2   320      // Q2 row offset (padded)
#define MT   640      // total Q rows (padded)
#define NKC  32       // K chunks of 32

typedef _Float16 half8 __attribute__((ext_vector_type(8)));
typedef float  float4v __attribute__((ext_vector_type(4)));

// ---------------- K1: sum of squares over Cf for each (b, r) ----------------
__global__ void k_sumsq(const float* __restrict__ img, float* __restrict__ sumsq) {
    int r  = threadIdx.x;          // 0..255
    int fc = blockIdx.x;           // 0..3
    int b  = blockIdx.y;           // 0..127
    const float* p = img + ((size_t)b * CF + (size_t)fc * 256) * RR + r;
    float acc = 0.f;
    #pragma unroll 4
    for (int f = 0; f < 256; ++f) { float v = p[(size_t)f * RR]; acc += v * v; }
    atomicAdd(&sumsq[b * RR + r], acc);
}

// ------------- K2: normalize + transpose + f16, K-blocked avT ---------------
// avT[b][kc][r][kk] f16, f = kc*32+kk
__global__ void k_avT(const float* __restrict__ img, const float* __restrict__ sumsq,
                      _Float16* __restrict__ avT) {
    int fc = blockIdx.x;   // 0..15  (64 f rows)
    int rc = blockIdx.y;   // 0..3   (64 r cols)
    int b  = blockIdx.z;
    int f0 = fc * 64, r0 = rc * 64;
    __shared__ float inv[64];
    __shared__ _Float16 tile[64][65];
    int t = threadIdx.x;
    if (t < 64) {
        float ss = sumsq[b * RR + r0 + t];
        inv[t] = 1.f / fmaxf(sqrtf(ss), 1e-12f);
    }
    __syncthreads();
    int fl = t >> 2;
    int rg = (t & 3) * 16;
    const float* p = img + ((size_t)(b * CF + f0 + fl)) * RR + r0 + rg;
    #pragma unroll
    for (int c = 0; c < 4; ++c) {
        float4 v = *(const float4*)(p + c * 4);
        tile[fl][rg + c*4 + 0] = (_Float16)(v.x * inv[rg + c*4 + 0]);
        tile[fl][rg + c*4 + 1] = (_Float16)(v.y * inv[rg + c*4 + 1]);
        tile[fl][rg + c*4 + 2] = (_Float16)(v.z * inv[rg + c*4 + 2]);
        tile[fl][rg + c*4 + 3] = (_Float16)(v.w * inv[rg + c*4 + 3]);
    }
    __syncthreads();
    int rl = t >> 2;
    int g  = t & 3;                      // fl = g*16 + j
    int kc = (f0 >> 5) + (g >> 1);
    int kkb = (g & 1) * 16;
    half8 o0, o1;
    #pragma unroll
    for (int j = 0; j < 8; ++j)  o0[j] = tile[g * 16 + j][rl];
    #pragma unroll
    for (int j = 0; j < 8; ++j)  o1[j] = tile[g * 16 + 8 + j][rl];
    _Float16* q = avT + (((size_t)(b * NKC + kc) * RR + (r0 + rl)) * 32 + kkb);
    *(half8*)(q)     = o0;
    *(half8*)(q + 8) = o1;
}

// ---------------- K3: row-normalize V -> vv (fp32) ----------------
__global__ void k_vv(const float* __restrict__ V, float* __restrict__ vv) {
    int i = blockIdx.x;   // 0..311
    int l = threadIdx.x;  // 0..63
    float s = 0.f;
    for (int v = l; v < DV; v += 64) { float x = V[i * DV + v]; s += x * x; }
    #pragma unroll
    for (int o = 32; o; o >>= 1) s += __shfl_down(s, o, 64);
    s = __shfl(s, 0, 64);
    float inv = 1.f / fmaxf(sqrtf(s), 1e-12f);
    for (int v = l; v < DV; v += 64) vv[i * DV + v] = V[i * DV + v] * inv;
}

// -------- K4: Q = [vv@W1 ; pad ; vv@W2 ; pad] -> K-blocked f16 Qb --------
// Qb[kc][i][kk], i in 0..639 (rows 312..319 and 632..639 zero)
__global__ void k_q(const float* __restrict__ vv, const float* __restrict__ W1,
                    const float* __restrict__ W2, _Float16* __restrict__ Qb) {
    int ib = blockIdx.x;                    // 0..79, rows i0..i0+7
    int f  = blockIdx.y * 256 + threadIdx.x;
    int i0 = ib * 8;
    float acc[8] = {0,0,0,0,0,0,0,0};
    bool zero = (ib == 39 || ib == 79);
    if (!zero) {
        const float* W = (ib < 39) ? W1 : W2;
        int v0 = (ib < 39) ? i0 : i0 - M2;
        for (int v = 0; v < DV; ++v) {
            float wv = W[(size_t)v * CF + f];
            #pragma unroll
            for (int ii = 0; ii < 8; ++ii) acc[ii] += vv[(v0 + ii) * DV + v] * wv;
        }
    }
    #pragma unroll
    for (int ii = 0; ii < 8; ++ii)
        Qb[((size_t)(f >> 5) * MT + (i0 + ii)) * 32 + (f & 31)] = (_Float16)acc[ii];
}

// ---------------- K5: batched GEMM + fused softmax-dot epilogue ----------------
// Block (t, b): C[64x256] = Qrows{t*32..+31, 320+t*32..+31} @ av_b ; out[b, t*32+i]
__launch_bounds__(256, 2)
__global__ void k_gemm(const _Float16* __restrict__ Qb, const _Float16* __restrict__ avT,
                       float* __restrict__ out) {
    int t   = blockIdx.x;    // 0..9
    int b   = blockIdx.y;    // 0..127
    int tid = threadIdx.x;
    int wave = tid >> 6, lane = tid & 63;
    int m_lane = lane & 15, quad = lane >> 4;

    __shared__ __align__(16) char smem[66560];
    _Float16* Al = (_Float16*)smem;               // [64][40]
    _Float16* Bl = (_Float16*)(smem + 5120);      // [256][40]
    float*    Cl = (float*)smem;                  // [64][260]

    float4v acc[16];
    #pragma unroll
    for (int n = 0; n < 16; ++n) acc[n] = (float4v){0.f, 0.f, 0.f, 0.f};

    int a_row = tid >> 2;
    int a_kk  = (tid & 3) * 8;
    int g_row = (a_row < 32) ? (t * 32 + a_row) : (M2 + t * 32 + (a_row - 32));
    int b_r   = tid >> 2;
    int b_kk  = (tid & 3) * 8;

    for (int kc = 0; kc < NKC; ++kc) {
        // stage A (64x32 f16)
        *(half8*)&Al[a_row * 40 + a_kk] =
            *(const half8*)&Qb[((size_t)kc * MT + g_row) * 32 + a_kk];
        // stage B (256x32 f16) — contiguous 16 KB block
        const _Float16* bsrc = avT + (size_t)(b * NKC + kc) * RR * 32;
        #pragma unroll
        for (int c = 0; c < 4; ++c) {
            int r = c * 64 + b_r;
            *(half8*)&Bl[r * 40 + b_kk] = *(const half8*)&bsrc[r * 32 + b_kk];
        }
        __syncthreads();
        half8 a = *(half8*)&Al[(wave * 16 + m_lane) * 40 + quad * 8];
        #pragma unroll
        for (int n0 = 0; n0 < 16; ++n0) {
            half8 bb = *(half8*)&Bl[(n0 * 16 + m_lane) * 40 + quad * 8];
            acc[n0] = __builtin_amdgcn_mfma_f32_16x16x32_f16(a, bb, acc[n0], 0, 0, 0);
        }
        __syncthreads();
    }

    // dump C to LDS: row = wave*16 + quad*4 + reg, col = n0*16 + m_lane
    #pragma unroll
    for (int n0 = 0; n0 < 16; ++n0) {
        #pragma unroll
        for (int rr = 0; rr < 4; ++rr)
            Cl[(wave * 16 + quad * 4 + rr) * 260 + n0 * 16 + m_lane] = acc[n0][rr];
    }
    __syncthreads();

    // epilogue: 8 threads per row, 32 rows
    int i_loc = tid >> 3, l8 = tid & 7;
    const float* c1 = &Cl[i_loc * 260];          // Q1 logits
    const float* c2 = &Cl[(32 + i_loc) * 260];   // Q2 values
    float m = -1e30f;
    for (int r = l8; r < RR; r += 8) m = fmaxf(m, c1[r]);
    #pragma unroll
    for (int o = 4; o; o >>= 1) m = fmaxf(m, __shfl_xor(m, o, 64));
    float s = 0.f, d = 0.f;
    for (int r = l8; r < RR; r += 8) {
        float e = expf(c1[r] - m);
        s += e; d += e * c2[r];
    }
    #pragma unroll
    for (int o = 4; o; o >>= 1) { s += __shfl_xor(s, o, 64); d += __shfl_xor(d, o, 64); }
    int i_g = t * 32 + i_loc;
    if (l8 == 0 && i_g < NA) out[b * NA + i_g] = d / s;
}

// ---------------- launcher ----------------
extern "C" void kernel_launch(void* const* d_in, const int* in_sizes, int n_in,
                              void* d_out, int out_size, void* d_ws, size_t ws_size,
                              hipStream_t stream) {
    const float* img = (const float*)d_in[0];
    const float* V   = (const float*)d_in[1];
    const float* W1  = (const float*)d_in[2];
    const float* W2  = (const float*)d_in[3];
    float* out = (float*)d_out;

    char* ws = (char*)d_ws;
    size_t off = 0;
    float*    sumsq = (float*)(ws + off);   off += (size_t)NB * RR * 4;            // 128 KB
    _Float16* avT   = (_Float16*)(ws + off); off += (size_t)NB * CF * RR * 2;      // 64 MB
    float*    vv    = (float*)(ws + off);   off += ((size_t)NA * DV * 4 + 255) & ~255ull;
    _Float16* Qb    = (_Float16*)(ws + off); off += (size_t)NKC * MT * 32 * 2;     // 1.25 MB

    hipMemsetAsync(sumsq, 0, (size_t)NB * RR * 4, stream);

    k_sumsq<<<dim3(4, NB), 256, 0, stream>>>(img, sumsq);
    k_avT<<<dim3(16, 4, NB), 256, 0, stream>>>(img, sumsq, avT);
    k_vv<<<dim3(NA), 64, 0, stream>>>(V, vv);
    k_q<<<dim3(80, 4), 256, 0, stream>>>(vv, W1, W2, Qb);
    k_gemm<<<dim3(10, NB), 256, 0, stream>>>(Qb, avT, out);
}

// Round 2
// 336.140 us; speedup vs baseline: 1.1938x; 1.1938x over previous
//
#include <hip/hip_runtime.h>
#include <math.h>

#define NB   128
#define CF   1024
#define RR   256
#define NA   312
#define DV   300
#define M2   320
#define MT   640
#define NKC  32

typedef _Float16 half8  __attribute__((ext_vector_type(8)));
typedef float float16v  __attribute__((ext_vector_type(16)));

__device__ __forceinline__ void gload16(const void* g, void* l) {
    __builtin_amdgcn_global_load_lds(
        (const __attribute__((address_space(1))) void*)g,
        (__attribute__((address_space(3))) void*)l, 16, 0, 0);
}

// ---- K1: fused sumsq + raw f16 transpose (img read ONCE; normalization deferred) ----
// avT[b][kc][r][kk] = (f16) img[b][kc*32+kk][r]  (raw, unnormalized)
__global__ void k_prep(const float* __restrict__ img, float* __restrict__ sumsq,
                       _Float16* __restrict__ avT) {
    int fs = blockIdx.x, rc = blockIdx.y, b = blockIdx.z;
    int r0 = rc * 64;
    int t = threadIdx.x;
    __shared__ __align__(16) char sm[64 * 65 * 4];
    _Float16 (*tile)[65] = (_Float16 (*)[65])sm;
    float    (*ssb)[65]  = (float    (*)[65])sm;
    int fl = t >> 2, cg = t & 3;     // load: row fl, col group cg*16
    int rl = t >> 2, g  = t & 3;     // transpose: col rl, row group g*16
    float ss[16];
    #pragma unroll
    for (int j = 0; j < 16; ++j) ss[j] = 0.f;

    for (int fc = 0; fc < 4; ++fc) {
        int f0 = fs * 256 + fc * 64;
        const float4* p4 = (const float4*)(img + ((size_t)(b * CF + f0 + fl)) * RR + r0 + cg * 16);
        float4 v0 = p4[0], v1 = p4[1], v2 = p4[2], v3 = p4[3];
        __syncthreads();   // previous iteration's tile readers done
        float xs[16] = {v0.x, v0.y, v0.z, v0.w, v1.x, v1.y, v1.z, v1.w,
                        v2.x, v2.y, v2.z, v2.w, v3.x, v3.y, v3.z, v3.w};
        #pragma unroll
        for (int j = 0; j < 16; ++j) {
            ss[j] += xs[j] * xs[j];
            tile[fl][cg * 16 + j] = (_Float16)xs[j];
        }
        __syncthreads();
        int kc  = (f0 >> 5) + (g >> 1);
        int kkb = (g & 1) * 16;
        half8 o0, o1;
        #pragma unroll
        for (int j = 0; j < 8; ++j) o0[j] = tile[g * 16 + j][rl];
        #pragma unroll
        for (int j = 0; j < 8; ++j) o1[j] = tile[g * 16 + 8 + j][rl];
        _Float16* q = avT + (((size_t)(b * NKC + kc) * RR + r0 + rl) * 32 + kkb);
        *(half8*)q       = o0;
        *(half8*)(q + 8) = o1;
    }
    __syncthreads();
    #pragma unroll
    for (int j = 0; j < 16; ++j) ssb[fl][cg * 16 + j] = ss[j];
    __syncthreads();
    if (t < 64) {
        float tot = 0.f;
        for (int f2 = 0; f2 < 64; ++f2) tot += ssb[f2][t];
        atomicAdd(&sumsq[b * RR + r0 + t], tot);
    }
}

// ---- K2: row-normalize V -> vv (fp32) ----
__global__ void k_vv(const float* __restrict__ V, float* __restrict__ vv) {
    int i = blockIdx.x;
    int l = threadIdx.x;
    float s = 0.f;
    for (int v = l; v < DV; v += 64) { float x = V[i * DV + v]; s += x * x; }
    #pragma unroll
    for (int o = 32; o; o >>= 1) s += __shfl_down(s, o, 64);
    s = __shfl(s, 0, 64);
    float inv = 1.f / fmaxf(sqrtf(s), 1e-12f);
    for (int v = l; v < DV; v += 64) vv[i * DV + v] = V[i * DV + v] * inv;
}

// ---- K3: Q = [vv@W1 ; pad ; vv@W2 ; pad] -> K-blocked f16 Qb[kc][i][kk] ----
__global__ void k_q(const float* __restrict__ vv, const float* __restrict__ W1,
                    const float* __restrict__ W2, _Float16* __restrict__ Qb) {
    int ib = blockIdx.x;
    int f  = blockIdx.y * 256 + threadIdx.x;
    int i0 = ib * 8;
    float acc[8] = {0,0,0,0,0,0,0,0};
    bool zero = (ib == 39 || ib == 79);
    if (!zero) {
        const float* W = (ib < 39) ? W1 : W2;
        int v0 = (ib < 39) ? i0 : i0 - M2;
        for (int v = 0; v < DV; ++v) {
            float wv = W[(size_t)v * CF + f];
            #pragma unroll
            for (int ii = 0; ii < 8; ++ii) acc[ii] += vv[(v0 + ii) * DV + v] * wv;
        }
    }
    #pragma unroll
    for (int ii = 0; ii < 8; ++ii)
        Qb[((size_t)(f >> 5) * MT + (i0 + ii)) * 32 + (f & 31)] = (_Float16)acc[ii];
}

// ---- K4: batched GEMM (32x32x16 MFMA, 2x2 reg-block) + fused scale/softmax/dot ----
// LDS layouts are k-block-major [kb][row][8] so global_load_lds stores AND
// ds_read_b128 frag reads are both stride-1 (conflict-free).
__launch_bounds__(256, 4)
__global__ void k_gemm(const _Float16* __restrict__ Qb, const _Float16* __restrict__ avT,
                       const float* __restrict__ sumsq, float* __restrict__ out) {
    int lin  = blockIdx.x;
    int xcd  = lin & 7;            // XCD swizzle: all 10 t-blocks of a batch on one XCD
    int slot = lin >> 3;
    int bq   = slot / 10;
    int t    = slot - bq * 10;
    int b    = bq * 8 + xcd;

    int tid = threadIdx.x;
    int lane = tid & 63, w = tid >> 6;
    int nl = lane & 31, kh = lane >> 5;

    __shared__ __align__(16) char smem[23168];
    _Float16* Al  = (_Float16*)smem;            // [kb4][row64][8] f16 = 4 KB
    _Float16* Bl  = (_Float16*)(smem + 4096);   // [kb4][r256][8]  f16 = 16 KB
    float* inv  = (float*)(smem + 20480);       // [256]
    float* mred = (float*)(smem + 21504);       // [32][4]
    float* mg   = (float*)(smem + 22016);       // [32]
    float* sred = (float*)(smem + 22144);       // [32][4]
    float* dred = (float*)(smem + 22656);       // [32][4]

    {   // deferred r-normalization factors
        float ssv = sumsq[b * RR + tid];
        inv[tid] = 1.f / fmaxf(sqrtf(ssv), 1e-12f);
    }

    float16v acc[2][2];   // [rowblk: 0=Q1,1=Q2][colblk]
    #pragma unroll
    for (int i = 0; i < 2; ++i)
        #pragma unroll
        for (int j = 0; j < 2; ++j)
            #pragma unroll
            for (int gidx = 0; gidx < 16; ++gidx) acc[i][j][gidx] = 0.f;

    // A staging: wave w stages kb=w for all 64 rows; lane -> row
    int arow = (lane < 32) ? (t * 32 + lane) : (M2 + t * 32 + (lane - 32));
    int brow = w * 64 + lane;   // B staging: wave w stages r-block w (all kb via rounds)

    for (int kc = 0; kc < NKC; ++kc) {
        const _Float16* abase = Qb + (size_t)kc * MT * 32;
        gload16(abase + (size_t)arow * 32 + w * 8, Al + w * 512);
        const _Float16* bbase = avT + (size_t)(b * NKC + kc) * RR * 32;
        #pragma unroll
        for (int c = 0; c < 4; ++c)
            gload16(bbase + (size_t)brow * 32 + c * 8, Bl + c * 2048 + w * 512);
        __syncthreads();
        #pragma unroll
        for (int ks = 0; ks < 2; ++ks) {
            int kb = ks * 2 + kh;
            half8 a0 = *(const half8*)(Al + (kb * 64 + nl) * 8);
            half8 a1 = *(const half8*)(Al + (kb * 64 + 32 + nl) * 8);
            half8 b0 = *(const half8*)(Bl + (kb * 256 + w * 64 + nl) * 8);
            half8 b1 = *(const half8*)(Bl + (kb * 256 + w * 64 + 32 + nl) * 8);
            acc[0][0] = __builtin_amdgcn_mfma_f32_32x32x16_f16(a0, b0, acc[0][0], 0, 0, 0);
            acc[0][1] = __builtin_amdgcn_mfma_f32_32x32x16_f16(a0, b1, acc[0][1], 0, 0, 0);
            acc[1][0] = __builtin_amdgcn_mfma_f32_32x32x16_f16(a1, b0, acc[1][0], 0, 0, 0);
            acc[1][1] = __builtin_amdgcn_mfma_f32_32x32x16_f16(a1, b1, acc[1][1], 0, 0, 0);
        }
        __syncthreads();
    }

    // ---- epilogue: scale columns by inv[r], softmax over r, dot with Q2 rows ----
    float iv0 = inv[w * 64 + nl];
    float iv1 = inv[w * 64 + 32 + nl];
    #pragma unroll
    for (int gidx = 0; gidx < 16; ++gidx) {
        acc[0][0][gidx] *= iv0; acc[0][1][gidx] *= iv1;
        acc[1][0][gidx] *= iv0; acc[1][1][gidx] *= iv1;
    }
    // per-row max over this wave's 64 cols (in-register + 32-lane shuffle)
    float mx[16];
    #pragma unroll
    for (int gidx = 0; gidx < 16; ++gidx) mx[gidx] = fmaxf(acc[0][0][gidx], acc[0][1][gidx]);
    #pragma unroll
    for (int off = 1; off <= 16; off <<= 1)
        #pragma unroll
        for (int gidx = 0; gidx < 16; ++gidx)
            mx[gidx] = fmaxf(mx[gidx], __shfl_xor(mx[gidx], off, 64));
    if (nl == 0) {
        #pragma unroll
        for (int gidx = 0; gidx < 16; ++gidx) {
            int row = (gidx & 3) + 8 * (gidx >> 2) + 4 * kh;
            mred[row * 4 + w] = mx[gidx];
        }
    }
    __syncthreads();
    if (tid < 32)
        mg[tid] = fmaxf(fmaxf(mred[tid * 4], mred[tid * 4 + 1]),
                        fmaxf(mred[tid * 4 + 2], mred[tid * 4 + 3]));
    __syncthreads();
    float sp[16], dp[16];
    #pragma unroll
    for (int gidx = 0; gidx < 16; ++gidx) {
        int row = (gidx & 3) + 8 * (gidx >> 2) + 4 * kh;
        float m  = mg[row];
        float e0 = __expf(acc[0][0][gidx] - m);
        float e1 = __expf(acc[0][1][gidx] - m);
        sp[gidx] = e0 + e1;
        dp[gidx] = e0 * acc[1][0][gidx] + e1 * acc[1][1][gidx];
    }
    #pragma unroll
    for (int off = 1; off <= 16; off <<= 1)
        #pragma unroll
        for (int gidx = 0; gidx < 16; ++gidx) {
            sp[gidx] += __shfl_xor(sp[gidx], off, 64);
            dp[gidx] += __shfl_xor(dp[gidx], off, 64);
        }
    if (nl == 0) {
        #pragma unroll
        for (int gidx = 0; gidx < 16; ++gidx) {
            int row = (gidx & 3) + 8 * (gidx >> 2) + 4 * kh;
            sred[row * 4 + w] = sp[gidx];
            dred[row * 4 + w] = dp[gidx];
        }
    }
    __syncthreads();
    if (tid < 32) {
        float s = sred[tid * 4] + sred[tid * 4 + 1] + sred[tid * 4 + 2] + sred[tid * 4 + 3];
        float d = dred[tid * 4] + dred[tid * 4 + 1] + dred[tid * 4 + 2] + dred[tid * 4 + 3];
        int ig = t * 32 + tid;
        if (ig < NA) out[b * NA + ig] = d / s;
    }
}

// ---- launcher ----
extern "C" void kernel_launch(void* const* d_in, const int* in_sizes, int n_in,
                              void* d_out, int out_size, void* d_ws, size_t ws_size,
                              hipStream_t stream) {
    const float* img = (const float*)d_in[0];
    const float* V   = (const float*)d_in[1];
    const float* W1  = (const float*)d_in[2];
    const float* W2  = (const float*)d_in[3];
    float* out = (float*)d_out;

    char* ws = (char*)d_ws;
    size_t off = 0;
    float*    sumsq = (float*)(ws + off);    off += (size_t)NB * RR * 4;
    _Float16* avT   = (_Float16*)(ws + off); off += (size_t)NB * CF * RR * 2;
    float*    vv    = (float*)(ws + off);    off += ((size_t)NA * DV * 4 + 255) & ~255ull;
    _Float16* Qb    = (_Float16*)(ws + off); off += (size_t)NKC * MT * 32 * 2;

    hipMemsetAsync(sumsq, 0, (size_t)NB * RR * 4, stream);

    k_prep<<<dim3(4, 4, NB), 256, 0, stream>>>(img, sumsq, avT);
    k_vv<<<dim3(NA), 64, 0, stream>>>(V, vv);
    k_q<<<dim3(80, 4), 256, 0, stream>>>(vv, W1, W2, Qb);
    k_gemm<<<dim3(1280), 256, 0, stream>>>(Qb, avT, sumsq, out);
}

// Round 4
// 325.111 us; speedup vs baseline: 1.2343x; 1.0339x over previous
//
#include <hip/hip_runtime.h>
#include <math.h>

#define NB   128
#define CF   1024
#define RR   256
#define NA   312
#define DV   300
#define M2   320
#define MT   640
#define NKC  32

typedef _Float16 half8  __attribute__((ext_vector_type(8)));
typedef float float16v  __attribute__((ext_vector_type(16)));

__device__ __forceinline__ void gload16(const void* g, void* l) {
    __builtin_amdgcn_global_load_lds(
        (const __attribute__((address_space(1))) void*)g,
        (__attribute__((address_space(3))) void*)l, 16, 0, 0);
}

// ---- K1: fused sumsq + raw f16 transpose (img read ONCE; normalization deferred) ----
// avT[b][kc][r][kk] = (f16) img[b][kc*32+kk][r]  (raw, unnormalized)
__global__ void k_prep(const float* __restrict__ img, float* __restrict__ sumsq,
                       _Float16* __restrict__ avT) {
    int fs = blockIdx.x, rc = blockIdx.y, b = blockIdx.z;
    int r0 = rc * 64;
    int t = threadIdx.x;
    __shared__ __align__(16) char sm[64 * 65 * 4];
    _Float16 (*tile)[65] = (_Float16 (*)[65])sm;
    float    (*ssb)[65]  = (float    (*)[65])sm;
    int fl = t >> 2, cg = t & 3;
    int rl = t >> 2, g  = t & 3;
    float ss[16];
    #pragma unroll
    for (int j = 0; j < 16; ++j) ss[j] = 0.f;

    for (int fc = 0; fc < 4; ++fc) {
        int f0 = fs * 256 + fc * 64;
        const float4* p4 = (const float4*)(img + ((size_t)(b * CF + f0 + fl)) * RR + r0 + cg * 16);
        float4 v0 = p4[0], v1 = p4[1], v2 = p4[2], v3 = p4[3];
        __syncthreads();
        float xs[16] = {v0.x, v0.y, v0.z, v0.w, v1.x, v1.y, v1.z, v1.w,
                        v2.x, v2.y, v2.z, v2.w, v3.x, v3.y, v3.z, v3.w};
        #pragma unroll
        for (int j = 0; j < 16; ++j) {
            ss[j] += xs[j] * xs[j];
            tile[fl][cg * 16 + j] = (_Float16)xs[j];
        }
        __syncthreads();
        int kc  = (f0 >> 5) + (g >> 1);
        int kkb = (g & 1) * 16;
        half8 o0, o1;
        #pragma unroll
        for (int j = 0; j < 8; ++j) o0[j] = tile[g * 16 + j][rl];
        #pragma unroll
        for (int j = 0; j < 8; ++j) o1[j] = tile[g * 16 + 8 + j][rl];
        _Float16* q = avT + (((size_t)(b * NKC + kc) * RR + r0 + rl) * 32 + kkb);
        *(half8*)q       = o0;
        *(half8*)(q + 8) = o1;
    }
    __syncthreads();
    #pragma unroll
    for (int j = 0; j < 16; ++j) ssb[fl][cg * 16 + j] = ss[j];
    __syncthreads();
    if (t < 64) {
        float tot = 0.f;
        for (int f2 = 0; f2 < 64; ++f2) tot += ssb[f2][t];
        atomicAdd(&sumsq[b * RR + r0 + t], tot);
    }
}

// ---- K2: Q = [l2norm(V)@W1 ; pad ; l2norm(V)@W2 ; pad] -> f16 Qb[kc][i][kk] ----
__global__ void k_q(const float* __restrict__ V, const float* __restrict__ W1,
                    const float* __restrict__ W2, _Float16* __restrict__ Qb) {
    int ib = blockIdx.x;                  // 0..79, rows i0..i0+7
    int f  = blockIdx.y * 256 + threadIdx.x;
    int i0 = ib * 8;
    int t  = threadIdx.x;
    __shared__ float inv8[8];
    float acc[8] = {0,0,0,0,0,0,0,0};
    bool zero = (ib == 39 || ib == 79);   // block-uniform
    int v0 = (ib < 40) ? i0 : i0 - M2;
    if (!zero) {
        int row = t >> 5, l32 = t & 31;
        float s = 0.f;
        for (int v = l32; v < DV; v += 32) { float x = V[(v0 + row) * DV + v]; s += x * x; }
        #pragma unroll
        for (int o = 16; o; o >>= 1) s += __shfl_xor(s, o, 32);
        if (l32 == 0) inv8[row] = 1.f / fmaxf(sqrtf(s), 1e-12f);
        __syncthreads();
        const float* W = (ib < 40) ? W1 : W2;
        for (int v = 0; v < DV; ++v) {
            float wv = W[(size_t)v * CF + f];
            #pragma unroll
            for (int ii = 0; ii < 8; ++ii) acc[ii] += V[(v0 + ii) * DV + v] * wv;
        }
        #pragma unroll
        for (int ii = 0; ii < 8; ++ii) acc[ii] *= inv8[ii];
    }
    #pragma unroll
    for (int ii = 0; ii < 8; ++ii)
        Qb[((size_t)(f >> 5) * MT + (i0 + ii)) * 32 + (f & 31)] = (_Float16)acc[ii];
}

// ---- K3: batched GEMM, double-buffered LDS DMA, one barrier per kc ----
// Manual 2x unroll: every global_load_lds LDS operand is a compile-time-
// constant offset (wave-uniform), no runtime-selected buffer pointers.
__launch_bounds__(256, 4)
__global__ void k_gemm(const _Float16* __restrict__ Qb, const _Float16* __restrict__ avT,
                       const float* __restrict__ sumsq, float* __restrict__ out) {
    int lin  = blockIdx.x;
    int xcd  = lin & 7;
    int slot = lin >> 3;
    int bq   = slot / 10;
    int t    = slot - bq * 10;
    int b    = bq * 8 + xcd;

    int tid = threadIdx.x;
    int lane = tid & 63, w = tid >> 6;
    int nl = lane & 31, kh = lane >> 5;

    // LDS: A0@0 (4K), A1@4K (4K), B0@8K (16K), B1@24K (16K) = 40960 B
    __shared__ __align__(16) char smem[40960];
    _Float16* A0 = (_Float16*)smem;
    _Float16* A1 = (_Float16*)(smem + 4096);
    _Float16* B0 = (_Float16*)(smem + 8192);
    _Float16* B1 = (_Float16*)(smem + 24576);
    // epilogue overlays (within A0/A1's dead 8 KB; valid only after k-loop):
    float* inv  = (float*)smem;            // [256]
    float* mred = (float*)(smem + 1024);   // [32][4]
    float* mg   = (float*)(smem + 1536);   // [32]
    float* sred = (float*)(smem + 1664);   // [32][4]
    float* dred = (float*)(smem + 2176);   // [32][4]

    float16v acc[2][2];
    #pragma unroll
    for (int i = 0; i < 2; ++i)
        #pragma unroll
        for (int j = 0; j < 2; ++j)
            #pragma unroll
            for (int gidx = 0; gidx < 16; ++gidx) acc[i][j][gidx] = 0.f;

    int arow = (lane < 32) ? (t * 32 + lane) : (M2 + t * 32 + (lane - 32));
    int brow = w * 64 + lane;
    const _Float16* bpanel = avT + (size_t)b * NKC * RR * 32;

    #define STAGE(kc_, Adst, Bdst)                                              \
        do {                                                                    \
            const _Float16* abase = Qb + (size_t)(kc_) * MT * 32;               \
            gload16(abase + (size_t)arow * 32 + w * 8, (Adst) + w * 512);       \
            const _Float16* bbase = bpanel + (size_t)(kc_) * RR * 32;           \
            gload16(bbase + (size_t)brow * 32 + 0 * 8, (Bdst) + 0 * 2048 + w * 512); \
            gload16(bbase + (size_t)brow * 32 + 1 * 8, (Bdst) + 1 * 2048 + w * 512); \
            gload16(bbase + (size_t)brow * 32 + 2 * 8, (Bdst) + 2 * 2048 + w * 512); \
            gload16(bbase + (size_t)brow * 32 + 3 * 8, (Bdst) + 3 * 2048 + w * 512); \
        } while (0)

    #define COMPUTE(Al, Bl)                                                     \
        do {                                                                    \
            _Pragma("unroll")                                                   \
            for (int ks = 0; ks < 2; ++ks) {                                    \
                int kb = ks * 2 + kh;                                           \
                half8 a0 = *(const half8*)((Al) + (kb * 64 + nl) * 8);          \
                half8 a1 = *(const half8*)((Al) + (kb * 64 + 32 + nl) * 8);     \
                half8 b0 = *(const half8*)((Bl) + (kb * 256 + w * 64 + nl) * 8);\
                half8 b1 = *(const half8*)((Bl) + (kb * 256 + w * 64 + 32 + nl) * 8);\
                acc[0][0] = __builtin_amdgcn_mfma_f32_32x32x16_f16(a0, b0, acc[0][0], 0, 0, 0); \
                acc[0][1] = __builtin_amdgcn_mfma_f32_32x32x16_f16(a0, b1, acc[0][1], 0, 0, 0); \
                acc[1][0] = __builtin_amdgcn_mfma_f32_32x32x16_f16(a1, b0, acc[1][0], 0, 0, 0); \
                acc[1][1] = __builtin_amdgcn_mfma_f32_32x32x16_f16(a1, b1, acc[1][1], 0, 0, 0); \
            }                                                                   \
        } while (0)

    STAGE(0, A0, B0);

    for (int kc = 0; kc < NKC; kc += 2) {
        __syncthreads();                 // buf0 (kc) staged; buf1 readers done
        STAGE(kc + 1, A1, B1);           // prefetch kc+1 (always valid: kc<=30)
        COMPUTE(A0, B0);
        __syncthreads();                 // buf1 (kc+1) staged; buf0 readers done
        if (kc + 2 < NKC) STAGE(kc + 2, A0, B0);
        COMPUTE(A1, B1);
    }
    __syncthreads();                     // all staging/reads done; overlay OK

    inv[tid] = 1.f / fmaxf(sqrtf(sumsq[b * RR + tid]), 1e-12f);
    __syncthreads();

    float iv0 = inv[w * 64 + nl];
    float iv1 = inv[w * 64 + 32 + nl];
    #pragma unroll
    for (int gidx = 0; gidx < 16; ++gidx) {
        acc[0][0][gidx] *= iv0; acc[0][1][gidx] *= iv1;
        acc[1][0][gidx] *= iv0; acc[1][1][gidx] *= iv1;
    }
    float mx[16];
    #pragma unroll
    for (int gidx = 0; gidx < 16; ++gidx) mx[gidx] = fmaxf(acc[0][0][gidx], acc[0][1][gidx]);
    #pragma unroll
    for (int off = 1; off <= 16; off <<= 1)
        #pragma unroll
        for (int gidx = 0; gidx < 16; ++gidx)
            mx[gidx] = fmaxf(mx[gidx], __shfl_xor(mx[gidx], off, 64));
    if (nl == 0) {
        #pragma unroll
        for (int gidx = 0; gidx < 16; ++gidx) {
            int row = (gidx & 3) + 8 * (gidx >> 2) + 4 * kh;
            mred[row * 4 + w] = mx[gidx];
        }
    }
    __syncthreads();
    if (tid < 32)
        mg[tid] = fmaxf(fmaxf(mred[tid * 4], mred[tid * 4 + 1]),
                        fmaxf(mred[tid * 4 + 2], mred[tid * 4 + 3]));
    __syncthreads();
    float sp[16], dp[16];
    #pragma unroll
    for (int gidx = 0; gidx < 16; ++gidx) {
        int row = (gidx & 3) + 8 * (gidx >> 2) + 4 * kh;
        float m  = mg[row];
        float e0 = __expf(acc[0][0][gidx] - m);
        float e1 = __expf(acc[0][1][gidx] - m);
        sp[gidx] = e0 + e1;
        dp[gidx] = e0 * acc[1][0][gidx] + e1 * acc[1][1][gidx];
    }
    #pragma unroll
    for (int off = 1; off <= 16; off <<= 1)
        #pragma unroll
        for (int gidx = 0; gidx < 16; ++gidx) {
            sp[gidx] += __shfl_xor(sp[gidx], off, 64);
            dp[gidx] += __shfl_xor(dp[gidx], off, 64);
        }
    if (nl == 0) {
        #pragma unroll
        for (int gidx = 0; gidx < 16; ++gidx) {
            int row = (gidx & 3) + 8 * (gidx >> 2) + 4 * kh;
            sred[row * 4 + w] = sp[gidx];
            dred[row * 4 + w] = dp[gidx];
        }
    }
    __syncthreads();
    if (tid < 32) {
        float s = sred[tid * 4] + sred[tid * 4 + 1] + sred[tid * 4 + 2] + sred[tid * 4 + 3];
        float d = dred[tid * 4] + dred[tid * 4 + 1] + dred[tid * 4 + 2] + dred[tid * 4 + 3];
        int ig = t * 32 + tid;
        if (ig < NA) out[b * NA + ig] = d / s;
    }
    #undef STAGE
    #undef COMPUTE
}

// ---- launcher ----
extern "C" void kernel_launch(void* const* d_in, const int* in_sizes, int n_in,
                              void* d_out, int out_size, void* d_ws, size_t ws_size,
                              hipStream_t stream) {
    const float* img = (const float*)d_in[0];
    const float* V   = (const float*)d_in[1];
    const float* W1  = (const float*)d_in[2];
    const float* W2  = (const float*)d_in[3];
    float* out = (float*)d_out;

    char* ws = (char*)d_ws;
    size_t off = 0;
    float*    sumsq = (float*)(ws + off);    off += (size_t)NB * RR * 4;
    _Float16* avT   = (_Float16*)(ws + off); off += (size_t)NB * CF * RR * 2;
    _Float16* Qb    = (_Float16*)(ws + off); off += (size_t)NKC * MT * 32 * 2;

    hipMemsetAsync(sumsq, 0, (size_t)NB * RR * 4, stream);

    k_prep<<<dim3(4, 4, NB), 256, 0, stream>>>(img, sumsq, avT);
    k_q<<<dim3(80, 4), 256, 0, stream>>>(V, W1, W2, Qb);
    k_gemm<<<dim3(1280), 256, 0, stream>>>(Qb, avT, sumsq, out);
}